// Round 1
// baseline (282.133 us; speedup 1.0000x reference)
//
#include <hip/hip_runtime.h>

typedef unsigned int u32;
typedef unsigned short u16;
typedef __attribute__((ext_vector_type(8))) __bf16 bf16x8;
typedef __attribute__((ext_vector_type(4))) float f32x4;

#define N_CAP 10
#define D_CAP 16
#define NN 160
#define KK 2048
#define BM 64
#define NSTEPS 64          // K-steps of 32
#define THREADS 640        // 10 waves: (wip 0..1) x (wjp 0..4)
#define HAT_STRIDE 165     // odd stride -> conflict-free routing reads
#define BSTEP 20480        // bytes per K-step in Wpack: 5 wjp * 64 lanes * 64 B

// Pre-split W, fragment-major. Record (s, wjp, lane) is 64 B: [bh0|bh1|bl0|bl1],
// each 8 bf16. bh0[j] = hi(W[32s + 8*(lane>>4) + j][32*wjp + (lane&15)]),
// bh1: col+16, bl*: truncated (x - hi(x)) parts. 1.31 MB total, L2-resident.
__device__ __align__(16) unsigned char Wpack_g[NSTEPS * BSTEP];

__device__ __forceinline__ u32 pack_hi(float f0, float f1) {
  u32 u0 = __builtin_bit_cast(u32, f0), u1 = __builtin_bit_cast(u32, f1);
  return (u0 >> 16) | (u1 & 0xFFFF0000u);
}
__device__ __forceinline__ float hi_part(float f) {
  u32 u = __builtin_bit_cast(u32, f) & 0xFFFF0000u;
  return __builtin_bit_cast(float, u);
}
union U4B8 { uint4 u; bf16x8 b; };

__global__ void pack_w(const float* __restrict__ W) {
  const int tid = blockIdx.x * 256 + threadIdx.x;   // one 16 B record per thread
  if (tid >= NSTEPS * 5 * 64 * 4) return;
  const int v = tid & 3;                 // 0:bh0 1:bh1 2:bl0 3:bl1
  const int lane = (tid >> 2) & 63;
  const int sw = tid >> 8;               // s*5 + wjp
  const int wjp = sw % 5;
  const int s = sw / 5;
  const int col = 32 * wjp + 16 * (v & 1) + (lane & 15);
  const int kb = 32 * s + 8 * (lane >> 4);
  u32 r[4];
#pragma unroll
  for (int jj = 0; jj < 4; ++jj) {
    float x0 = W[(size_t)(kb + 2 * jj) * NN + col];
    float x1 = W[(size_t)(kb + 2 * jj + 1) * NN + col];
    if (v >= 2) { x0 -= hi_part(x0); x1 -= hi_part(x1); }
    r[jj] = pack_hi(x0, x1);
  }
  uint4 o; o.x = r[0]; o.y = r[1]; o.z = r[2]; o.w = r[3];
  *(uint4*)(Wpack_g + (size_t)tid * 16) = o;
}

__global__ __launch_bounds__(THREADS, 2) void capsule_fused(
    const float* __restrict__ X, float* __restrict__ out) {
  __shared__ float hat[BM * HAT_STRIDE];   // 42240 B, epilogue-only

  const int t = threadIdx.x;
  const int rbase = blockIdx.x * BM;
  const int lane = t & 63;
  const int w = t >> 6;                  // wave 0..9
  const int wip = (w >= 5) ? 1 : 0;      // row half
  const int wjp = w - 5 * wip;           // col group of 32
  const int l15 = lane & 15;
  const int q = lane >> 4;

  // A: direct per-wave global loads (L1/L2 absorb the 5x col-wave re-read)
  const float* pA0 = X + (size_t)(rbase + 32 * wip + l15) * KK + 8 * q;
  const float* pA1 = pA0 + 16 * KK;
  // B: pre-packed bf16 fragments, 64 B/lane/step, fully coalesced
  const unsigned char* pB = Wpack_g + ((size_t)wjp * 64 + lane) * 64;

  f32x4 acc00 = {0.f,0.f,0.f,0.f}, acc01 = {0.f,0.f,0.f,0.f};
  f32x4 acc10 = {0.f,0.f,0.f,0.f}, acc11 = {0.f,0.f,0.f,0.f};

  // double-buffered registers: A 2 steps deep, B 1 step deep
  float4 aE0, aE1, aE2, aE3, aO0, aO1, aO2, aO3;
  uint4 bE0, bE1, bE2, bE3, bO0, bO1, bO2, bO3;

  aE0 = *(const float4*)(pA0);      aE1 = *(const float4*)(pA0 + 4);
  aE2 = *(const float4*)(pA1);      aE3 = *(const float4*)(pA1 + 4);
  aO0 = *(const float4*)(pA0 + 32); aO1 = *(const float4*)(pA0 + 36);
  aO2 = *(const float4*)(pA1 + 32); aO3 = *(const float4*)(pA1 + 36);
  bE0 = *(const uint4*)(pB);        bE1 = *(const uint4*)(pB + 16);
  bE2 = *(const uint4*)(pB + 32);   bE3 = *(const uint4*)(pB + 48);

#define STEP(S, A0, A1, A2, A3, BC0, BC1, BC2, BC3, BN0, BN1, BN2, BN3)          \
  {                                                                              \
    U4B8 ah0, al0, ah1, al1;                                                     \
    ah0.u.x = pack_hi(A0.x, A0.y); ah0.u.y = pack_hi(A0.z, A0.w);                \
    ah0.u.z = pack_hi(A1.x, A1.y); ah0.u.w = pack_hi(A1.z, A1.w);                \
    { float l0 = A0.x - hi_part(A0.x), l1 = A0.y - hi_part(A0.y);                \
      float l2 = A0.z - hi_part(A0.z), l3 = A0.w - hi_part(A0.w);                \
      float l4 = A1.x - hi_part(A1.x), l5 = A1.y - hi_part(A1.y);                \
      float l6 = A1.z - hi_part(A1.z), l7 = A1.w - hi_part(A1.w);                \
      al0.u.x = pack_hi(l0, l1); al0.u.y = pack_hi(l2, l3);                      \
      al0.u.z = pack_hi(l4, l5); al0.u.w = pack_hi(l6, l7); }                    \
    ah1.u.x = pack_hi(A2.x, A2.y); ah1.u.y = pack_hi(A2.z, A2.w);                \
    ah1.u.z = pack_hi(A3.x, A3.y); ah1.u.w = pack_hi(A3.z, A3.w);                \
    { float l0 = A2.x - hi_part(A2.x), l1 = A2.y - hi_part(A2.y);                \
      float l2 = A2.z - hi_part(A2.z), l3 = A2.w - hi_part(A2.w);                \
      float l4 = A3.x - hi_part(A3.x), l5 = A3.y - hi_part(A3.y);                \
      float l6 = A3.z - hi_part(A3.z), l7 = A3.w - hi_part(A3.w);                \
      al1.u.x = pack_hi(l0, l1); al1.u.y = pack_hi(l2, l3);                      \
      al1.u.z = pack_hi(l4, l5); al1.u.w = pack_hi(l6, l7); }                    \
    if ((S) + 2 < NSTEPS) {                                                      \
      A0 = *(const float4*)(pA0 + ((S) + 2) * 32);                               \
      A1 = *(const float4*)(pA0 + ((S) + 2) * 32 + 4);                           \
      A2 = *(const float4*)(pA1 + ((S) + 2) * 32);                               \
      A3 = *(const float4*)(pA1 + ((S) + 2) * 32 + 4);                           \
    }                                                                            \
    if ((S) + 1 < NSTEPS) {                                                      \
      const unsigned char* bp = pB + ((size_t)((S) + 1)) * BSTEP;                \
      BN0 = *(const uint4*)(bp);      BN1 = *(const uint4*)(bp + 16);            \
      BN2 = *(const uint4*)(bp + 32); BN3 = *(const uint4*)(bp + 48);            \
    }                                                                            \
    U4B8 ub0, ub1, ub2, ub3;                                                     \
    ub0.u = BC0; ub1.u = BC1; ub2.u = BC2; ub3.u = BC3;                          \
    acc00 = __builtin_amdgcn_mfma_f32_16x16x32_bf16(ah0.b, ub0.b, acc00, 0,0,0); \
    acc00 = __builtin_amdgcn_mfma_f32_16x16x32_bf16(ah0.b, ub2.b, acc00, 0,0,0); \
    acc00 = __builtin_amdgcn_mfma_f32_16x16x32_bf16(al0.b, ub0.b, acc00, 0,0,0); \
    acc01 = __builtin_amdgcn_mfma_f32_16x16x32_bf16(ah0.b, ub1.b, acc01, 0,0,0); \
    acc01 = __builtin_amdgcn_mfma_f32_16x16x32_bf16(ah0.b, ub3.b, acc01, 0,0,0); \
    acc01 = __builtin_amdgcn_mfma_f32_16x16x32_bf16(al0.b, ub1.b, acc01, 0,0,0); \
    acc10 = __builtin_amdgcn_mfma_f32_16x16x32_bf16(ah1.b, ub0.b, acc10, 0,0,0); \
    acc10 = __builtin_amdgcn_mfma_f32_16x16x32_bf16(ah1.b, ub2.b, acc10, 0,0,0); \
    acc10 = __builtin_amdgcn_mfma_f32_16x16x32_bf16(al1.b, ub0.b, acc10, 0,0,0); \
    acc11 = __builtin_amdgcn_mfma_f32_16x16x32_bf16(ah1.b, ub1.b, acc11, 0,0,0); \
    acc11 = __builtin_amdgcn_mfma_f32_16x16x32_bf16(ah1.b, ub3.b, acc11, 0,0,0); \
    acc11 = __builtin_amdgcn_mfma_f32_16x16x32_bf16(al1.b, ub1.b, acc11, 0,0,0); \
  }

#pragma unroll 1
  for (int s = 0; s < NSTEPS; s += 2) {
    STEP(s,     aE0, aE1, aE2, aE3, bE0, bE1, bE2, bE3, bO0, bO1, bO2, bO3)
    STEP(s + 1, aO0, aO1, aO2, aO3, bO0, bO1, bO2, bO3, bE0, bE1, bE2, bE3)
  }
#undef STEP

  // ---- exchange hat through LDS (first and only barrier) ----
#pragma unroll
  for (int r = 0; r < 4; ++r) {
    // C/D layout: col = lane&15, row = (lane>>4)*4 + reg
    const int rowb = 32 * wip + 4 * q + r;
    const int colb = 32 * wjp + l15;
    hat[rowb * HAT_STRIDE + colb]             = acc00[r];
    hat[rowb * HAT_STRIDE + colb + 16]        = acc01[r];
    hat[(rowb + 16) * HAT_STRIDE + colb]      = acc10[r];
    hat[(rowb + 16) * HAT_STRIDE + colb + 16] = acc11[r];
  }
  __syncthreads();

  // ---- routing: 8 lanes per row, register-resident hat, shfl reductions ----
  if (t < BM * 8) {
    const int r = t >> 3;
    const int d0 = t & 7;
    float h0[N_CAP], h1[N_CAP];
#pragma unroll
    for (int n = 0; n < N_CAP; ++n) {
      h0[n] = hat[r * HAT_STRIDE + n * D_CAP + d0];
      h1[n] = hat[r * HAT_STRIDE + n * D_CAP + d0 + 8];
    }
    float bb[N_CAP];
#pragma unroll
    for (int n = 0; n < N_CAP; ++n) bb[n] = 0.f;
    float v0 = 0.f, v1 = 0.f;
#pragma unroll
    for (int it = 0; it < 3; ++it) {
      float mx = bb[0];
#pragma unroll
      for (int n = 1; n < N_CAP; ++n) mx = fmaxf(mx, bb[n]);
      float c[N_CAP], se = 0.f;
#pragma unroll
      for (int n = 0; n < N_CAP; ++n) { c[n] = __expf(bb[n] - mx); se += c[n]; }
      const float inv = 1.f / se;
      float s0 = 0.f, s1 = 0.f;
#pragma unroll
      for (int n = 0; n < N_CAP; ++n) { s0 += c[n] * h0[n]; s1 += c[n] * h1[n]; }
      s0 *= inv; s1 *= inv;
      float s2 = s0 * s0 + s1 * s1;
      s2 += __shfl_xor(s2, 1);
      s2 += __shfl_xor(s2, 2);
      s2 += __shfl_xor(s2, 4);
      const float scale = s2 / ((1.f + s2) * sqrtf(s2 + 1e-7f));
      v0 = scale * s0; v1 = scale * s1;
      if (it < 2) {
#pragma unroll
        for (int n = 0; n < N_CAP; ++n) {
          float dd = h0[n] * v0 + h1[n] * v1;
          dd += __shfl_xor(dd, 1);
          dd += __shfl_xor(dd, 2);
          dd += __shfl_xor(dd, 4);
          bb[n] += dd;
        }
      }
    }
    out[(size_t)(rbase + r) * D_CAP + d0] = v0;
    out[(size_t)(rbase + r) * D_CAP + d0 + 8] = v1;
  }
}

extern "C" void kernel_launch(void* const* d_in, const int* in_sizes, int n_in,
                              void* d_out, int out_size, void* d_ws, size_t ws_size,
                              hipStream_t stream) {
  const float* X = (const float*)d_in[0];   // inputs [16384][2048] f32
  const float* W = (const float*)d_in[1];   // kernel [2048][160] f32
  if (n_in >= 2 && in_sizes[0] == KK * NN) {  // defensive: identify by element count
    X = (const float*)d_in[1];
    W = (const float*)d_in[0];
  }
  (void)d_ws; (void)ws_size; (void)out_size;
  pack_w<<<(NSTEPS * 5 * 64 * 4 + 255) / 256, 256, 0, stream>>>(W);
  capsule_fused<<<16384 / BM, THREADS, 0, stream>>>(X, (float*)d_out);
}

// Round 2
// 239.418 us; speedup vs baseline: 1.1784x; 1.1784x over previous
//
#include <hip/hip_runtime.h>

typedef unsigned int u32;
typedef unsigned short u16;
typedef __attribute__((ext_vector_type(8))) __bf16 bf16x8;
typedef __attribute__((ext_vector_type(4))) float f32x4;

#define N_CAP 10
#define D_CAP 16
#define NN 160
#define KK 2048
#define BM 64
#define NSTEPS 64           // K-steps of 32 floats
#define THREADS 704         // 10 compute waves + 1 producer wave
#define HAT_STRIDE 165      // odd stride -> conflict-free routing reads
#define BSTEP 20480         // bytes per K-step in Wpack: 5 wjp * 64 lanes * 64 B
#define TILE_B 8192         // one staged A tile: 64 rows x 32 f32 (128 B/row)
#define NBUF 3              // staging ring depth

// Pre-split W, fragment-major. Record (s, wjp, lane) is 64 B: [bh0|bh1|bl0|bl1],
// each 8 bf16. 1.31 MB total, L2-resident.
__device__ __align__(16) unsigned char Wpack_g[NSTEPS * BSTEP];

__device__ __forceinline__ u32 pack_hi(float f0, float f1) {
  u32 u0 = __builtin_bit_cast(u32, f0), u1 = __builtin_bit_cast(u32, f1);
  return (u0 >> 16) | (u1 & 0xFFFF0000u);
}
__device__ __forceinline__ float hi_part(float f) {
  u32 u = __builtin_bit_cast(u32, f) & 0xFFFF0000u;
  return __builtin_bit_cast(float, u);
}
union U4B8 { uint4 u; bf16x8 b; };

__device__ __forceinline__ void split2(const float4& x, const float4& y,
                                       bf16x8& h, bf16x8& l) {
  U4B8 hh, ll;
  hh.u.x = pack_hi(x.x, x.y); hh.u.y = pack_hi(x.z, x.w);
  hh.u.z = pack_hi(y.x, y.y); hh.u.w = pack_hi(y.z, y.w);
  float l0 = x.x - hi_part(x.x), l1 = x.y - hi_part(x.y);
  float l2 = x.z - hi_part(x.z), l3 = x.w - hi_part(x.w);
  float l4 = y.x - hi_part(y.x), l5 = y.y - hi_part(y.y);
  float l6 = y.z - hi_part(y.z), l7 = y.w - hi_part(y.w);
  ll.u.x = pack_hi(l0, l1); ll.u.y = pack_hi(l2, l3);
  ll.u.z = pack_hi(l4, l5); ll.u.w = pack_hi(l6, l7);
  h = hh.b; l = ll.b;
}

__global__ void pack_w(const float* __restrict__ W) {
  const int tid = blockIdx.x * 256 + threadIdx.x;   // one 16 B record per thread
  if (tid >= NSTEPS * 5 * 64 * 4) return;
  const int v = tid & 3;                 // 0:bh0 1:bh1 2:bl0 3:bl1
  const int lane = (tid >> 2) & 63;
  const int sw = tid >> 8;               // s*5 + wjp
  const int wjp = sw % 5;
  const int s = sw / 5;
  const int col = 32 * wjp + 16 * (v & 1) + (lane & 15);
  const int kb = 32 * s + 8 * (lane >> 4);
  u32 r[4];
#pragma unroll
  for (int jj = 0; jj < 4; ++jj) {
    float x0 = W[(size_t)(kb + 2 * jj) * NN + col];
    float x1 = W[(size_t)(kb + 2 * jj + 1) * NN + col];
    if (v >= 2) { x0 -= hi_part(x0); x1 -= hi_part(x1); }
    r[jj] = pack_hi(x0, x1);
  }
  uint4 o; o.x = r[0]; o.y = r[1]; o.z = r[2]; o.w = r[3];
  *(uint4*)(Wpack_g + (size_t)tid * 16) = o;
}

// async global->LDS DMA, 16 B per lane; lds base must be wave-uniform
#define GLOAD(gp, lp) __builtin_amdgcn_global_load_lds( \
    (const __attribute__((address_space(1))) u32*)(gp), \
    (__attribute__((address_space(3))) u32*)(lp), 16, 0, 0)
#define BARRIER() asm volatile("s_barrier" ::: "memory")

__global__ __launch_bounds__(THREADS, 1) void capsule_fused(
    const float* __restrict__ X, float* __restrict__ out) {
  // first NBUF*TILE_B bytes double as the A staging ring during the K-loop;
  // whole region becomes hat[64][165] f32 after the final loop barrier.
  __shared__ __align__(16) char smem[BM * HAT_STRIDE * 4];   // 42240 B
  char* As = smem;
  float* hat = (float*)smem;

  const int t = threadIdx.x;
  const int rbase = blockIdx.x * BM;
  const int lane = t & 63;
  const int w = t >> 6;                  // wave 0..10

  if (w == 10) {
    // ================= producer wave =================
    // lane -> (row-in-8-group = lane>>3, dest chunk = lane&7).
    // Source chunk is XOR-swizzled so that LDS slot (r, c') holds X chunk
    // c = c' ^ (r&7)  (linear DMA dest + swizzled source = swizzled tile).
    const float* g0 = X + (size_t)(rbase + (lane >> 3)) * KK
                        + (size_t)(((lane & 7) ^ (lane >> 3)) * 4);
#define STAGE(sv, bv) do {                                        \
    const float* gs_ = g0 + (size_t)(sv) * 32;                    \
    char* lb_ = As + (bv) * TILE_B;                               \
    GLOAD(gs_,           lb_);                                    \
    GLOAD(gs_ +  8 * KK, lb_ + 1024);                             \
    GLOAD(gs_ + 16 * KK, lb_ + 2048);                             \
    GLOAD(gs_ + 24 * KK, lb_ + 3072);                             \
    GLOAD(gs_ + 32 * KK, lb_ + 4096);                             \
    GLOAD(gs_ + 40 * KK, lb_ + 5120);                             \
    GLOAD(gs_ + 48 * KK, lb_ + 6144);                             \
    GLOAD(gs_ + 56 * KK, lb_ + 7168);                             \
  } while (0)
    STAGE(0, 0);
    STAGE(1, 1);
    asm volatile("s_waitcnt vmcnt(8)" ::: "memory");  // stage(0) landed
    BARRIER();
    int pj = 2;
#pragma unroll 1
    for (int s = 0; s < NSTEPS; ++s) {
      if (s + 2 < NSTEPS) {
        STAGE(s + 2, pj);
        // allow the 8 just-issued to stay in flight; require stage(s+1) done
        asm volatile("s_waitcnt vmcnt(8)" ::: "memory");
      } else {
        asm volatile("s_waitcnt vmcnt(0)" ::: "memory");
      }
      BARRIER();
      pj = (pj == 2) ? 0 : pj + 1;
    }
#undef STAGE
  } else {
    // ================= consumer waves =================
    const int wip = (w >= 5) ? 1 : 0;      // row half
    const int wjp = w - 5 * wip;           // col group of 32
    const int l15 = lane & 15;
    const int q = lane >> 4;
    const int r0 = 32 * wip + l15;
    const int r1 = r0 + 16;
    const int c0 = 2 * q, c1 = 2 * q + 1;  // 16B chunks of the 32-float row
    // swizzled read offsets (lane-constant)
    const int o00 = (r0 >> 3) * 1024 + (r0 & 7) * 128 + ((c0 ^ (r0 & 7)) << 4);
    const int o01 = (r0 >> 3) * 1024 + (r0 & 7) * 128 + ((c1 ^ (r0 & 7)) << 4);
    const int o10 = (r1 >> 3) * 1024 + (r1 & 7) * 128 + ((c0 ^ (r1 & 7)) << 4);
    const int o11 = (r1 >> 3) * 1024 + (r1 & 7) * 128 + ((c1 ^ (r1 & 7)) << 4);
    const unsigned char* pB = Wpack_g + ((size_t)(wjp * 64 + lane)) * 64;

    f32x4 acc00 = {0.f,0.f,0.f,0.f}, acc01 = {0.f,0.f,0.f,0.f};
    f32x4 acc10 = {0.f,0.f,0.f,0.f}, acc11 = {0.f,0.f,0.f,0.f};

    BARRIER();                              // tile 0 staged
    int ci = 0;
#pragma unroll 1
    for (int s = 0; s < NSTEPS; ++s) {
      const uint4* bp4 = (const uint4*)(pB + (size_t)s * BSTEP);
      uint4 B0 = bp4[0], B1 = bp4[1], B2 = bp4[2], B3 = bp4[3];
      const char* cb = As + ci * TILE_B;
      float4 A00 = *(const float4*)(cb + o00);
      float4 A01 = *(const float4*)(cb + o01);
      float4 A10 = *(const float4*)(cb + o10);
      float4 A11 = *(const float4*)(cb + o11);
      bf16x8 ah0, al0, ah1, al1;
      split2(A00, A01, ah0, al0);
      split2(A10, A11, ah1, al1);
      U4B8 ub0, ub1, ub2, ub3;
      ub0.u = B0; ub1.u = B1; ub2.u = B2; ub3.u = B3;
      acc00 = __builtin_amdgcn_mfma_f32_16x16x32_bf16(ah0, ub0.b, acc00, 0,0,0);
      acc00 = __builtin_amdgcn_mfma_f32_16x16x32_bf16(ah0, ub2.b, acc00, 0,0,0);
      acc00 = __builtin_amdgcn_mfma_f32_16x16x32_bf16(al0, ub0.b, acc00, 0,0,0);
      acc01 = __builtin_amdgcn_mfma_f32_16x16x32_bf16(ah0, ub1.b, acc01, 0,0,0);
      acc01 = __builtin_amdgcn_mfma_f32_16x16x32_bf16(ah0, ub3.b, acc01, 0,0,0);
      acc01 = __builtin_amdgcn_mfma_f32_16x16x32_bf16(al0, ub1.b, acc01, 0,0,0);
      acc10 = __builtin_amdgcn_mfma_f32_16x16x32_bf16(ah1, ub0.b, acc10, 0,0,0);
      acc10 = __builtin_amdgcn_mfma_f32_16x16x32_bf16(ah1, ub2.b, acc10, 0,0,0);
      acc10 = __builtin_amdgcn_mfma_f32_16x16x32_bf16(al1, ub0.b, acc10, 0,0,0);
      acc11 = __builtin_amdgcn_mfma_f32_16x16x32_bf16(ah1, ub1.b, acc11, 0,0,0);
      acc11 = __builtin_amdgcn_mfma_f32_16x16x32_bf16(ah1, ub3.b, acc11, 0,0,0);
      acc11 = __builtin_amdgcn_mfma_f32_16x16x32_bf16(al1, ub1.b, acc11, 0,0,0);
      BARRIER();
      ci = (ci == 2) ? 0 : ci + 1;
    }
    // staging ring dead now; write hat into the same smem
#pragma unroll
    for (int r = 0; r < 4; ++r) {
      // C/D layout: col = lane&15, row = (lane>>4)*4 + reg
      const int rowb = 32 * wip + 4 * q + r;
      const int colb = 32 * wjp + l15;
      hat[rowb * HAT_STRIDE + colb]             = acc00[r];
      hat[rowb * HAT_STRIDE + colb + 16]        = acc01[r];
      hat[(rowb + 16) * HAT_STRIDE + colb]      = acc10[r];
      hat[(rowb + 16) * HAT_STRIDE + colb + 16] = acc11[r];
    }
  }
  __syncthreads();

  // ---- routing: 8 lanes per row, register-resident hat, shfl reductions ----
  if (t < BM * 8) {
    const int r = t >> 3;
    const int d0 = t & 7;
    float h0[N_CAP], h1[N_CAP];
#pragma unroll
    for (int n = 0; n < N_CAP; ++n) {
      h0[n] = hat[r * HAT_STRIDE + n * D_CAP + d0];
      h1[n] = hat[r * HAT_STRIDE + n * D_CAP + d0 + 8];
    }
    float bb[N_CAP];
#pragma unroll
    for (int n = 0; n < N_CAP; ++n) bb[n] = 0.f;
    float v0 = 0.f, v1 = 0.f;
#pragma unroll
    for (int it = 0; it < 3; ++it) {
      float mx = bb[0];
#pragma unroll
      for (int n = 1; n < N_CAP; ++n) mx = fmaxf(mx, bb[n]);
      float c[N_CAP], se = 0.f;
#pragma unroll
      for (int n = 0; n < N_CAP; ++n) { c[n] = __expf(bb[n] - mx); se += c[n]; }
      const float inv = 1.f / se;
      float s0 = 0.f, s1 = 0.f;
#pragma unroll
      for (int n = 0; n < N_CAP; ++n) { s0 += c[n] * h0[n]; s1 += c[n] * h1[n]; }
      s0 *= inv; s1 *= inv;
      float s2 = s0 * s0 + s1 * s1;
      s2 += __shfl_xor(s2, 1);
      s2 += __shfl_xor(s2, 2);
      s2 += __shfl_xor(s2, 4);
      const float scale = s2 / ((1.f + s2) * sqrtf(s2 + 1e-7f));
      v0 = scale * s0; v1 = scale * s1;
      if (it < 2) {
#pragma unroll
        for (int n = 0; n < N_CAP; ++n) {
          float dd = h0[n] * v0 + h1[n] * v1;
          dd += __shfl_xor(dd, 1);
          dd += __shfl_xor(dd, 2);
          dd += __shfl_xor(dd, 4);
          bb[n] += dd;
        }
      }
    }
    out[(size_t)(rbase + r) * D_CAP + d0] = v0;
    out[(size_t)(rbase + r) * D_CAP + d0 + 8] = v1;
  }
}

extern "C" void kernel_launch(void* const* d_in, const int* in_sizes, int n_in,
                              void* d_out, int out_size, void* d_ws, size_t ws_size,
                              hipStream_t stream) {
  const float* X = (const float*)d_in[0];   // inputs [16384][2048] f32
  const float* W = (const float*)d_in[1];   // kernel [2048][160] f32
  if (n_in >= 2 && in_sizes[0] == KK * NN) {  // defensive: identify by element count
    X = (const float*)d_in[1];
    W = (const float*)d_in[0];
  }
  (void)d_ws; (void)ws_size; (void)out_size;
  pack_w<<<(NSTEPS * 5 * 64 * 4 + 255) / 256, 256, 0, stream>>>(W);
  capsule_fused<<<16384 / BM, THREADS, 0, stream>>>(X, (float*)d_out);
}

// Round 3
// 225.219 us; speedup vs baseline: 1.2527x; 1.0630x over previous
//
#include <hip/hip_runtime.h>

typedef unsigned int u32;
typedef unsigned short u16;
typedef __attribute__((ext_vector_type(8))) __bf16 bf16x8;
typedef __attribute__((ext_vector_type(4))) float f32x4;

#define N_CAP 10
#define D_CAP 16
#define NN 160
#define KK 2048
#define BM 64
#define NSTEPS 64           // K-steps of 32 floats
#define NITER 32            // 2 K-steps per iteration
#define THREADS 704         // 10 compute waves + 1 producer wave
#define HAT_STRIDE 165      // odd stride -> conflict-free routing reads
#define BSTEP 20480         // bytes per K-step in Wpack: 5 wjp * 64 lanes * 64 B
#define TILE2 16384         // one staged A tile: 2 K-steps = 64 rows x 64 f32
#define NBUF 3              // staging ring depth

// Pre-split W, fragment-major. Record (s, wjp, lane) is 64 B: [bh0|bh1|bl0|bl1],
// each 8 bf16. 1.31 MB total, L2/L3-resident.
__device__ __align__(16) unsigned char Wpack_g[NSTEPS * BSTEP];

__device__ __forceinline__ u32 pack_hi(float f0, float f1) {
  u32 u0 = __builtin_bit_cast(u32, f0), u1 = __builtin_bit_cast(u32, f1);
  return (u0 >> 16) | (u1 & 0xFFFF0000u);
}
__device__ __forceinline__ float hi_part(float f) {
  u32 u = __builtin_bit_cast(u32, f) & 0xFFFF0000u;
  return __builtin_bit_cast(float, u);
}
union U4B8 { uint4 u; bf16x8 b; };

__device__ __forceinline__ void split2(const float4& x, const float4& y,
                                       bf16x8& h, bf16x8& l) {
  U4B8 hh, ll;
  hh.u.x = pack_hi(x.x, x.y); hh.u.y = pack_hi(x.z, x.w);
  hh.u.z = pack_hi(y.x, y.y); hh.u.w = pack_hi(y.z, y.w);
  float l0 = x.x - hi_part(x.x), l1 = x.y - hi_part(x.y);
  float l2 = x.z - hi_part(x.z), l3 = x.w - hi_part(x.w);
  float l4 = y.x - hi_part(y.x), l5 = y.y - hi_part(y.y);
  float l6 = y.z - hi_part(y.z), l7 = y.w - hi_part(y.w);
  ll.u.x = pack_hi(l0, l1); ll.u.y = pack_hi(l2, l3);
  ll.u.z = pack_hi(l4, l5); ll.u.w = pack_hi(l6, l7);
  h = hh.b; l = ll.b;
}

__global__ void pack_w(const float* __restrict__ W) {
  const int tid = blockIdx.x * 256 + threadIdx.x;   // one 16 B record per thread
  if (tid >= NSTEPS * 5 * 64 * 4) return;
  const int v = tid & 3;                 // 0:bh0 1:bh1 2:bl0 3:bl1
  const int lane = (tid >> 2) & 63;
  const int sw = tid >> 8;               // s*5 + wjp
  const int wjp = sw % 5;
  const int s = sw / 5;
  const int col = 32 * wjp + 16 * (v & 1) + (lane & 15);
  const int kb = 32 * s + 8 * (lane >> 4);
  u32 r[4];
#pragma unroll
  for (int jj = 0; jj < 4; ++jj) {
    float x0 = W[(size_t)(kb + 2 * jj) * NN + col];
    float x1 = W[(size_t)(kb + 2 * jj + 1) * NN + col];
    if (v >= 2) { x0 -= hi_part(x0); x1 -= hi_part(x1); }
    r[jj] = pack_hi(x0, x1);
  }
  uint4 o; o.x = r[0]; o.y = r[1]; o.z = r[2]; o.w = r[3];
  *(uint4*)(Wpack_g + (size_t)tid * 16) = o;
}

// async global->LDS DMA, 16 B per lane; lds base must be wave-uniform
#define GLOAD(gp, lp) __builtin_amdgcn_global_load_lds( \
    (const __attribute__((address_space(1))) u32*)(gp), \
    (__attribute__((address_space(3))) u32*)(lp), 16, 0, 0)
#define BARRIER() asm volatile("s_barrier" ::: "memory")
// pinned global load: compiler can't sink/drop it; data readable only after
// a hand-counted s_waitcnt vmcnt(N) (vector loads don't scoreboard dests)
#define BLOAD(dst, addr) \
  asm volatile("global_load_dwordx4 %0, %1, off" : "=v"(dst) : "v"(addr))

__global__ __launch_bounds__(THREADS, 1) void capsule_fused(
    const float* __restrict__ X, float* __restrict__ out) {
  __shared__ __align__(16) char As[NBUF * TILE2];        // 48 KiB A ring
  __shared__ __align__(16) float hat[BM * HAT_STRIDE];   // 42.24 KiB

  const int t = threadIdx.x;
  const int rbase = blockIdx.x * BM;
  const int lane = t & 63;
  const int w = t >> 6;                  // wave 0..10

  if (w == 10) {
    // ================= producer wave =================
    // lane -> (row-in-8-group = lane>>3, dest chunk = lane&7); source chunk
    // XOR-swizzled so LDS slot (r, c') holds X chunk c = c' ^ (r&7).
    const float* g0 = X + (size_t)(rbase + (lane >> 3)) * KK
                        + (size_t)(((lane & 7) ^ (lane >> 3)) * 4);
#define STAGE2(IT, BV) do {                                       \
    const float* ga_ = g0 + (size_t)(2 * (IT)) * 32;              \
    char* la_ = As + (BV) * TILE2;                                \
    GLOAD(ga_,           la_);                                    \
    GLOAD(ga_ +  8 * KK, la_ + 1024);                             \
    GLOAD(ga_ + 16 * KK, la_ + 2048);                             \
    GLOAD(ga_ + 24 * KK, la_ + 3072);                             \
    GLOAD(ga_ + 32 * KK, la_ + 4096);                             \
    GLOAD(ga_ + 40 * KK, la_ + 5120);                             \
    GLOAD(ga_ + 48 * KK, la_ + 6144);                             \
    GLOAD(ga_ + 56 * KK, la_ + 7168);                             \
    const float* gb_ = ga_ + 32;                                  \
    char* lb_ = la_ + 8192;                                       \
    GLOAD(gb_,           lb_);                                    \
    GLOAD(gb_ +  8 * KK, lb_ + 1024);                             \
    GLOAD(gb_ + 16 * KK, lb_ + 2048);                             \
    GLOAD(gb_ + 24 * KK, lb_ + 3072);                             \
    GLOAD(gb_ + 32 * KK, lb_ + 4096);                             \
    GLOAD(gb_ + 40 * KK, lb_ + 5120);                             \
    GLOAD(gb_ + 48 * KK, lb_ + 6144);                             \
    GLOAD(gb_ + 56 * KK, lb_ + 7168);                             \
  } while (0)
    STAGE2(0, 0);
    STAGE2(1, 1);
    asm volatile("s_waitcnt vmcnt(16)" ::: "memory");  // tile 0 landed
    BARRIER();
    int pj = 2;
#pragma unroll 1
    for (int i = 0; i < NITER; ++i) {
      if (i + 2 < NITER) {
        STAGE2(i + 2, pj);
        asm volatile("s_waitcnt vmcnt(16)" ::: "memory");  // tile i+1 landed
      } else {
        asm volatile("s_waitcnt vmcnt(0)" ::: "memory");
      }
      BARRIER();
      pj = (pj == 2) ? 0 : pj + 1;
    }
#undef STAGE2
  } else {
    // ================= consumer waves =================
    const int wip = (w >= 5) ? 1 : 0;      // row half
    const int wjp = w - 5 * wip;           // col group of 32
    const int l15 = lane & 15;
    const int q = lane >> 4;
    const int r0 = 32 * wip + l15;
    const int r1 = r0 + 16;
    const int c0 = 2 * q, c1 = 2 * q + 1;  // 16B chunks of a 32-float row
    const int o00 = (r0 >> 3) * 1024 + (r0 & 7) * 128 + ((c0 ^ (r0 & 7)) << 4);
    const int o01 = (r0 >> 3) * 1024 + (r0 & 7) * 128 + ((c1 ^ (r0 & 7)) << 4);
    const int o10 = (r1 >> 3) * 1024 + (r1 & 7) * 128 + ((c0 ^ (r1 & 7)) << 4);
    const int o11 = (r1 >> 3) * 1024 + (r1 & 7) * 128 + ((c1 ^ (r1 & 7)) << 4);
    const unsigned char* pBw = Wpack_g + ((size_t)(wjp * 64 + lane)) * 64;

    f32x4 acc00 = {0.f,0.f,0.f,0.f}, acc01 = {0.f,0.f,0.f,0.f};
    f32x4 acc10 = {0.f,0.f,0.f,0.f}, acc11 = {0.f,0.f,0.f,0.f};

    uint4 Ba[8], Bb[8];
    // prologue: pin B for iteration 0 (steps 0,1)
    BLOAD(Ba[0], pBw);                BLOAD(Ba[1], pBw + 16);
    BLOAD(Ba[2], pBw + 32);           BLOAD(Ba[3], pBw + 48);
    BLOAD(Ba[4], pBw + BSTEP);        BLOAD(Ba[5], pBw + BSTEP + 16);
    BLOAD(Ba[6], pBw + BSTEP + 32);   BLOAD(Ba[7], pBw + BSTEP + 48);

    BARRIER();                              // tile 0 staged
    int ci = 0;

#define MFMA12(AH0, AL0, AH1, AL1, B0, B1, B2, B3)                               \
    {                                                                            \
      U4B8 u0, u1, u2, u3;                                                       \
      u0.u = B0; u1.u = B1; u2.u = B2; u3.u = B3;                                \
      acc00 = __builtin_amdgcn_mfma_f32_16x16x32_bf16(AH0, u0.b, acc00, 0,0,0);  \
      acc00 = __builtin_amdgcn_mfma_f32_16x16x32_bf16(AH0, u2.b, acc00, 0,0,0);  \
      acc00 = __builtin_amdgcn_mfma_f32_16x16x32_bf16(AL0, u0.b, acc00, 0,0,0);  \
      acc01 = __builtin_amdgcn_mfma_f32_16x16x32_bf16(AH0, u1.b, acc01, 0,0,0);  \
      acc01 = __builtin_amdgcn_mfma_f32_16x16x32_bf16(AH0, u3.b, acc01, 0,0,0);  \
      acc01 = __builtin_amdgcn_mfma_f32_16x16x32_bf16(AL0, u1.b, acc01, 0,0,0);  \
      acc10 = __builtin_amdgcn_mfma_f32_16x16x32_bf16(AH1, u0.b, acc10, 0,0,0);  \
      acc10 = __builtin_amdgcn_mfma_f32_16x16x32_bf16(AH1, u2.b, acc10, 0,0,0);  \
      acc10 = __builtin_amdgcn_mfma_f32_16x16x32_bf16(AL1, u0.b, acc10, 0,0,0);  \
      acc11 = __builtin_amdgcn_mfma_f32_16x16x32_bf16(AH1, u1.b, acc11, 0,0,0);  \
      acc11 = __builtin_amdgcn_mfma_f32_16x16x32_bf16(AH1, u3.b, acc11, 0,0,0);  \
      acc11 = __builtin_amdgcn_mfma_f32_16x16x32_bf16(AL1, u1.b, acc11, 0,0,0);  \
    }

#define ITER(I, BC, BN)                                                          \
    {                                                                            \
      const char* cb = As + ci * TILE2;                                          \
      float4 A00a = *(const float4*)(cb + o00);                                  \
      float4 A01a = *(const float4*)(cb + o01);                                  \
      float4 A10a = *(const float4*)(cb + o10);                                  \
      float4 A11a = *(const float4*)(cb + o11);                                  \
      float4 A00b = *(const float4*)(cb + 8192 + o00);                           \
      float4 A01b = *(const float4*)(cb + 8192 + o01);                           \
      float4 A10b = *(const float4*)(cb + 8192 + o10);                           \
      float4 A11b = *(const float4*)(cb + 8192 + o11);                           \
      const unsigned char* bp = pBw + (size_t)((((I) + 1) & (NITER - 1)) * 2) * BSTEP; \
      BLOAD(BN[0], bp);              BLOAD(BN[1], bp + 16);                      \
      BLOAD(BN[2], bp + 32);         BLOAD(BN[3], bp + 48);                      \
      BLOAD(BN[4], bp + BSTEP);      BLOAD(BN[5], bp + BSTEP + 16);              \
      BLOAD(BN[6], bp + BSTEP + 32); BLOAD(BN[7], bp + BSTEP + 48);              \
      bf16x8 ah0a, al0a, ah1a, al1a, ah0b, al0b, ah1b, al1b;                     \
      split2(A00a, A01a, ah0a, al0a);                                            \
      split2(A10a, A11a, ah1a, al1a);                                            \
      split2(A00b, A01b, ah0b, al0b);                                            \
      split2(A10b, A11b, ah1b, al1b);                                            \
      asm volatile("s_waitcnt vmcnt(8)" ::: "memory");  /* BC retired */         \
      __builtin_amdgcn_sched_barrier(0);                                         \
      MFMA12(ah0a, al0a, ah1a, al1a, BC[0], BC[1], BC[2], BC[3])                 \
      MFMA12(ah0b, al0b, ah1b, al1b, BC[4], BC[5], BC[6], BC[7])                 \
      BARRIER();                                                                 \
      ci = (ci == 2) ? 0 : ci + 1;                                               \
    }

#pragma unroll 1
    for (int i = 0; i < NITER; i += 2) {
      ITER(i,     Ba, Bb)
      ITER(i + 1, Bb, Ba)
    }
#undef ITER
#undef MFMA12

    // write hat (separate LDS region; ring is dead)
#pragma unroll
    for (int r = 0; r < 4; ++r) {
      // C/D layout: col = lane&15, row = (lane>>4)*4 + reg
      const int rowb = 32 * wip + 4 * q + r;
      const int colb = 32 * wjp + l15;
      hat[rowb * HAT_STRIDE + colb]             = acc00[r];
      hat[rowb * HAT_STRIDE + colb + 16]        = acc01[r];
      hat[(rowb + 16) * HAT_STRIDE + colb]      = acc10[r];
      hat[(rowb + 16) * HAT_STRIDE + colb + 16] = acc11[r];
    }
  }
  __syncthreads();

  // ---- routing: 8 lanes per row, register-resident hat, shfl reductions ----
  if (t < BM * 8) {
    const int r = t >> 3;
    const int d0 = t & 7;
    float h0[N_CAP], h1[N_CAP];
#pragma unroll
    for (int n = 0; n < N_CAP; ++n) {
      h0[n] = hat[r * HAT_STRIDE + n * D_CAP + d0];
      h1[n] = hat[r * HAT_STRIDE + n * D_CAP + d0 + 8];
    }
    float bb[N_CAP];
#pragma unroll
    for (int n = 0; n < N_CAP; ++n) bb[n] = 0.f;
    float v0 = 0.f, v1 = 0.f;
#pragma unroll
    for (int it = 0; it < 3; ++it) {
      float mx = bb[0];
#pragma unroll
      for (int n = 1; n < N_CAP; ++n) mx = fmaxf(mx, bb[n]);
      float c[N_CAP], se = 0.f;
#pragma unroll
      for (int n = 0; n < N_CAP; ++n) { c[n] = __expf(bb[n] - mx); se += c[n]; }
      const float inv = 1.f / se;
      float s0 = 0.f, s1 = 0.f;
#pragma unroll
      for (int n = 0; n < N_CAP; ++n) { s0 += c[n] * h0[n]; s1 += c[n] * h1[n]; }
      s0 *= inv; s1 *= inv;
      float s2 = s0 * s0 + s1 * s1;
      s2 += __shfl_xor(s2, 1);
      s2 += __shfl_xor(s2, 2);
      s2 += __shfl_xor(s2, 4);
      const float scale = s2 / ((1.f + s2) * sqrtf(s2 + 1e-7f));
      v0 = scale * s0; v1 = scale * s1;
      if (it < 2) {
#pragma unroll
        for (int n = 0; n < N_CAP; ++n) {
          float dd = h0[n] * v0 + h1[n] * v1;
          dd += __shfl_xor(dd, 1);
          dd += __shfl_xor(dd, 2);
          dd += __shfl_xor(dd, 4);
          bb[n] += dd;
        }
      }
    }
    out[(size_t)(rbase + r) * D_CAP + d0] = v0;
    out[(size_t)(rbase + r) * D_CAP + d0 + 8] = v1;
  }
}

extern "C" void kernel_launch(void* const* d_in, const int* in_sizes, int n_in,
                              void* d_out, int out_size, void* d_ws, size_t ws_size,
                              hipStream_t stream) {
  const float* X = (const float*)d_in[0];   // inputs [16384][2048] f32
  const float* W = (const float*)d_in[1];   // kernel [2048][160] f32
  if (n_in >= 2 && in_sizes[0] == KK * NN) {  // defensive: identify by element count
    X = (const float*)d_in[1];
    W = (const float*)d_in[0];
  }
  (void)d_ws; (void)ws_size; (void)out_size;
  pack_w<<<(NSTEPS * 5 * 64 * 4 + 255) / 256, 256, 0, stream>>>(W);
  capsule_fused<<<16384 / BM, THREADS, 0, stream>>>(X, (float*)d_out);
}

// Round 5
// 208.343 us; speedup vs baseline: 1.3542x; 1.0810x over previous
//
#include <hip/hip_runtime.h>

typedef unsigned int u32;
typedef unsigned short u16;
typedef __attribute__((ext_vector_type(8))) __bf16 bf16x8;
typedef __attribute__((ext_vector_type(4))) float f32x4;

#define N_CAP 10
#define D_CAP 16
#define NN 160
#define KK 2048
#define BM 64
#define NSTEPS 64           // K-steps of 32 floats
#define THREADS 704         // 10 compute waves + 1 producer wave
#define HAT_STRIDE 165      // odd stride -> conflict-free routing reads
#define BSTEP 20480         // bytes per K-step of Wpack: 4 v * 5 wjp * 64 lanes * 16 B
#define ATILE 8192          // one staged A step: 64 rows x 32 f32
#define NBUF 3              // ring depth (A and B)

// Pre-split W, DMA-friendly layout: 16 B record (s, v, wjp, lane) at
// Wpack_g[(((s*4 + v)*5 + wjp)*64 + lane) * 16].
// v: 0=bh0 1=bh1 2=bl0 3=bl1.  bh0[j] = hi(W[32s + 8*(lane>>4) + j][32wjp + (lane&15)]),
// bh1: col+16, bl*: truncated low parts. 1.31 MB total, L2/L3-resident.
__device__ __align__(16) unsigned char Wpack_g[NSTEPS * BSTEP];

__device__ __forceinline__ u32 pack_hi(float f0, float f1) {
  u32 u0 = __builtin_bit_cast(u32, f0), u1 = __builtin_bit_cast(u32, f1);
  return (u0 >> 16) | (u1 & 0xFFFF0000u);
}
__device__ __forceinline__ float hi_part(float f) {
  u32 u = __builtin_bit_cast(u32, f) & 0xFFFF0000u;
  return __builtin_bit_cast(float, u);
}
union U4B8 { uint4 u; bf16x8 b; };

__device__ __forceinline__ void split2(const float4& x, const float4& y,
                                       bf16x8& h, bf16x8& l) {
  U4B8 hh, ll;
  hh.u.x = pack_hi(x.x, x.y); hh.u.y = pack_hi(x.z, x.w);
  hh.u.z = pack_hi(y.x, y.y); hh.u.w = pack_hi(y.z, y.w);
  float l0 = x.x - hi_part(x.x), l1 = x.y - hi_part(x.y);
  float l2 = x.z - hi_part(x.z), l3 = x.w - hi_part(x.w);
  float l4 = y.x - hi_part(y.x), l5 = y.y - hi_part(y.y);
  float l6 = y.z - hi_part(y.z), l7 = y.w - hi_part(y.w);
  ll.u.x = pack_hi(l0, l1); ll.u.y = pack_hi(l2, l3);
  ll.u.z = pack_hi(l4, l5); ll.u.w = pack_hi(l6, l7);
  h = hh.b; l = ll.b;
}

__device__ __forceinline__ void mfma12(bf16x8 ah0, bf16x8 al0, bf16x8 ah1,
                                       bf16x8 al1, bf16x8 bh0, bf16x8 bh1,
                                       bf16x8 bl0, bf16x8 bl1, f32x4& a00,
                                       f32x4& a01, f32x4& a10, f32x4& a11) {
  a00 = __builtin_amdgcn_mfma_f32_16x16x32_bf16(ah0, bh0, a00, 0, 0, 0);
  a00 = __builtin_amdgcn_mfma_f32_16x16x32_bf16(ah0, bl0, a00, 0, 0, 0);
  a00 = __builtin_amdgcn_mfma_f32_16x16x32_bf16(al0, bh0, a00, 0, 0, 0);
  a01 = __builtin_amdgcn_mfma_f32_16x16x32_bf16(ah0, bh1, a01, 0, 0, 0);
  a01 = __builtin_amdgcn_mfma_f32_16x16x32_bf16(ah0, bl1, a01, 0, 0, 0);
  a01 = __builtin_amdgcn_mfma_f32_16x16x32_bf16(al0, bh1, a01, 0, 0, 0);
  a10 = __builtin_amdgcn_mfma_f32_16x16x32_bf16(ah1, bh0, a10, 0, 0, 0);
  a10 = __builtin_amdgcn_mfma_f32_16x16x32_bf16(ah1, bl0, a10, 0, 0, 0);
  a10 = __builtin_amdgcn_mfma_f32_16x16x32_bf16(al1, bh0, a10, 0, 0, 0);
  a11 = __builtin_amdgcn_mfma_f32_16x16x32_bf16(ah1, bh1, a11, 0, 0, 0);
  a11 = __builtin_amdgcn_mfma_f32_16x16x32_bf16(ah1, bl1, a11, 0, 0, 0);
  a11 = __builtin_amdgcn_mfma_f32_16x16x32_bf16(al1, bh1, a11, 0, 0, 0);
}

__global__ void pack_w(const float* __restrict__ W) {
  const int tid = blockIdx.x * 256 + threadIdx.x;   // one 16 B record per thread
  if (tid >= NSTEPS * 4 * 5 * 64) return;
  const int lane = tid & 63;
  const int rest = tid >> 6;
  const int wjp = rest % 5;
  const int rest2 = rest / 5;
  const int v = rest2 & 3;               // 0:bh0 1:bh1 2:bl0 3:bl1
  const int s = rest2 >> 2;
  const int col = 32 * wjp + 16 * (v & 1) + (lane & 15);
  const int kb = 32 * s + 8 * (lane >> 4);
  u32 r[4];
#pragma unroll
  for (int jj = 0; jj < 4; ++jj) {
    float x0 = W[(size_t)(kb + 2 * jj) * NN + col];
    float x1 = W[(size_t)(kb + 2 * jj + 1) * NN + col];
    if (v >= 2) { x0 -= hi_part(x0); x1 -= hi_part(x1); }
    r[jj] = pack_hi(x0, x1);
  }
  uint4 o; o.x = r[0]; o.y = r[1]; o.z = r[2]; o.w = r[3];
  *(uint4*)(Wpack_g + (size_t)tid * 16) = o;
}

// async global->LDS DMA, 16 B per lane; lds base must be wave-uniform
#define GLOAD(gp, lp) __builtin_amdgcn_global_load_lds( \
    (const __attribute__((address_space(1))) u32*)(gp), \
    (__attribute__((address_space(3))) u32*)(lp), 16, 0, 0)
#define BARRIER() asm volatile("s_barrier" ::: "memory")

__global__ __launch_bounds__(THREADS, 1) void capsule_fused(
    const float* __restrict__ X, float* __restrict__ out) {
  __shared__ __align__(16) char AsA[NBUF * ATILE];       // 24 KiB A ring
  __shared__ __align__(16) char AsB[NBUF * BSTEP];       // 60 KiB B ring
  __shared__ __align__(16) float hat[BM * HAT_STRIDE];   // 42.24 KiB
  // total 128,256 B -> 1 block/CU (grid = 256 = #CUs)

  const int t = threadIdx.x;
  const int rbase = blockIdx.x * BM;
  const int lane = t & 63;
  const int w = t >> 6;                  // wave 0..10

  if (w == 10) {
    // ================= producer wave =================
    // A: lane -> (row-in-8-group = lane>>3, dest chunk = lane&7); source chunk
    // XOR-swizzled so LDS slot (r, c') holds X chunk c = c' ^ (r&7).
    const float* g0 = X + (size_t)(rbase + (lane >> 3)) * KK
                        + (size_t)(((lane & 7) ^ (lane >> 3)) * 4);
    // B: straight linear copy of the 20 KB step slice (20 x 1 KB chunks).
    const unsigned char* gw0 = Wpack_g + (size_t)lane * 16;
#define STAGE(S, BV) do {                                         \
    const float* ga_ = g0 + (size_t)(S) * 32;                     \
    char* la_ = AsA + (BV) * ATILE;                               \
    GLOAD(ga_,           la_);                                    \
    GLOAD(ga_ +  8 * KK, la_ + 1024);                             \
    GLOAD(ga_ + 16 * KK, la_ + 2048);                             \
    GLOAD(ga_ + 24 * KK, la_ + 3072);                             \
    GLOAD(ga_ + 32 * KK, la_ + 4096);                             \
    GLOAD(ga_ + 40 * KK, la_ + 5120);                             \
    GLOAD(ga_ + 48 * KK, la_ + 6144);                             \
    GLOAD(ga_ + 56 * KK, la_ + 7168);                             \
    const unsigned char* gw_ = gw0 + (size_t)(S) * BSTEP;         \
    char* lw_ = AsB + (BV) * BSTEP;                               \
    _Pragma("unroll")                                             \
    for (int c_ = 0; c_ < 20; ++c_)                               \
      GLOAD(gw_ + c_ * 1024, lw_ + c_ * 1024);                    \
  } while (0)
    STAGE(0, 0);
    STAGE(1, 1);
    asm volatile("s_waitcnt vmcnt(28)" ::: "memory");  // tile 0 landed
    BARRIER();
    int pj = 2;
#pragma unroll 1
    for (int i = 0; i < NSTEPS; ++i) {
      if (i + 2 < NSTEPS) {
        STAGE(i + 2, pj);
        asm volatile("s_waitcnt vmcnt(28)" ::: "memory");  // tile i+1 landed
      } else {
        asm volatile("s_waitcnt vmcnt(0)" ::: "memory");
      }
      BARRIER();
      pj = (pj == 2) ? 0 : pj + 1;
    }
#undef STAGE
  } else {
    // ================= consumer waves =================
    // No global loads, no hand-counted vmcnt here: only ds_read + VALU + MFMA.
    const int wip = (w >= 5) ? 1 : 0;      // row half
    const int wjp = w - 5 * wip;           // col group of 32
    const int l15 = lane & 15;
    const int q = lane >> 4;
    const int r0 = 32 * wip + l15;
    const int r1 = r0 + 16;
    const int c0 = 2 * q, c1 = 2 * q + 1;  // 16B chunks of a 32-float row
    const int o00 = (r0 >> 3) * 1024 + (r0 & 7) * 128 + ((c0 ^ (r0 & 7)) << 4);
    const int o01 = (r0 >> 3) * 1024 + (r0 & 7) * 128 + ((c1 ^ (r0 & 7)) << 4);
    const int o10 = (r1 >> 3) * 1024 + (r1 & 7) * 128 + ((c0 ^ (r1 & 7)) << 4);
    const int o11 = (r1 >> 3) * 1024 + (r1 & 7) * 128 + ((c1 ^ (r1 & 7)) << 4);
    // B in LDS: chunk (v, wjp) at (v*5 + wjp)*1024, lane record at +lane*16
    const int ob = wjp * 1024 + lane * 16;

    f32x4 acc00 = {0.f,0.f,0.f,0.f}, acc01 = {0.f,0.f,0.f,0.f};
    f32x4 acc10 = {0.f,0.f,0.f,0.f}, acc11 = {0.f,0.f,0.f,0.f};

    BARRIER();                              // tile 0 staged
    int ci = 0;
#pragma unroll 1
    for (int i = 0; i < NSTEPS; ++i) {
      const char* ca = AsA + ci * ATILE;
      const char* cbb = AsB + ci * BSTEP + ob;
      bf16x8 bh0 = *(const bf16x8*)(cbb);
      bf16x8 bh1 = *(const bf16x8*)(cbb + 5120);
      bf16x8 bl0 = *(const bf16x8*)(cbb + 10240);
      bf16x8 bl1 = *(const bf16x8*)(cbb + 15360);
      float4 A00 = *(const float4*)(ca + o00);
      float4 A01 = *(const float4*)(ca + o01);
      float4 A10 = *(const float4*)(ca + o10);
      float4 A11 = *(const float4*)(ca + o11);
      bf16x8 ah0, al0, ah1, al1;
      split2(A00, A01, ah0, al0);
      split2(A10, A11, ah1, al1);
      mfma12(ah0, al0, ah1, al1, bh0, bh1, bl0, bl1,
             acc00, acc01, acc10, acc11);
      BARRIER();
      ci = (ci == 2) ? 0 : ci + 1;
    }

    // write hat (separate LDS region; ring is dead)
#pragma unroll
    for (int r = 0; r < 4; ++r) {
      // C/D layout: col = lane&15, row = (lane>>4)*4 + reg
      const int rowb = 32 * wip + 4 * q + r;
      const int colb = 32 * wjp + l15;
      hat[rowb * HAT_STRIDE + colb]             = acc00[r];
      hat[rowb * HAT_STRIDE + colb + 16]        = acc01[r];
      hat[(rowb + 16) * HAT_STRIDE + colb]      = acc10[r];
      hat[(rowb + 16) * HAT_STRIDE + colb + 16] = acc11[r];
    }
  }
  __syncthreads();

  // ---- routing: 8 lanes per row, register-resident hat, shfl reductions ----
  if (t < BM * 8) {
    const int r = t >> 3;
    const int d0 = t & 7;
    float h0[N_CAP], h1[N_CAP];
#pragma unroll
    for (int n = 0; n < N_CAP; ++n) {
      h0[n] = hat[r * HAT_STRIDE + n * D_CAP + d0];
      h1[n] = hat[r * HAT_STRIDE + n * D_CAP + d0 + 8];
    }
    float bb[N_CAP];
#pragma unroll
    for (int n = 0; n < N_CAP; ++n) bb[n] = 0.f;
    float v0 = 0.f, v1 = 0.f;
#pragma unroll
    for (int it = 0; it < 3; ++it) {
      float mx = bb[0];
#pragma unroll
      for (int n = 1; n < N_CAP; ++n) mx = fmaxf(mx, bb[n]);
      float c[N_CAP], se = 0.f;
#pragma unroll
      for (int n = 0; n < N_CAP; ++n) { c[n] = __expf(bb[n] - mx); se += c[n]; }
      const float inv = 1.f / se;
      float s0 = 0.f, s1 = 0.f;
#pragma unroll
      for (int n = 0; n < N_CAP; ++n) { s0 += c[n] * h0[n]; s1 += c[n] * h1[n]; }
      s0 *= inv; s1 *= inv;
      float s2 = s0 * s0 + s1 * s1;
      s2 += __shfl_xor(s2, 1);
      s2 += __shfl_xor(s2, 2);
      s2 += __shfl_xor(s2, 4);
      const float scale = s2 / ((1.f + s2) * sqrtf(s2 + 1e-7f));
      v0 = scale * s0; v1 = scale * s1;
      if (it < 2) {
#pragma unroll
        for (int n = 0; n < N_CAP; ++n) {
          float dd = h0[n] * v0 + h1[n] * v1;
          dd += __shfl_xor(dd, 1);
          dd += __shfl_xor(dd, 2);
          dd += __shfl_xor(dd, 4);
          bb[n] += dd;
        }
      }
    }
    out[(size_t)(rbase + r) * D_CAP + d0] = v0;
    out[(size_t)(rbase + r) * D_CAP + d0 + 8] = v1;
  }
}

extern "C" void kernel_launch(void* const* d_in, const int* in_sizes, int n_in,
                              void* d_out, int out_size, void* d_ws, size_t ws_size,
                              hipStream_t stream) {
  const float* X = (const float*)d_in[0];   // inputs [16384][2048] f32
  const float* W = (const float*)d_in[1];   // kernel [2048][160] f32
  if (n_in >= 2 && in_sizes[0] == KK * NN) {  // defensive: identify by element count
    X = (const float*)d_in[1];
    W = (const float*)d_in[0];
  }
  (void)d_ws; (void)ws_size; (void)out_size;
  pack_w<<<(NSTEPS * 4 * 5 * 64 + 255) / 256, 256, 0, stream>>>(W);
  capsule_fused<<<16384 / BM, THREADS, 0, stream>>>(X, (float*)d_out);
}